// Round 12
// baseline (131.224 us; speedup 1.0000x reference)
//
#include <hip/hip_runtime.h>

// LangNN via SWAPPED-operand 16x16x32 bf16 MFMA. B=131072, H=25, A=18.
// Round-12: PHASE-MAJOR activation. r6-r11 plateaued at ~60% VALUBusy with
// ~50us of issue in ~100us wall: the element-major ACT chain (7 dependent
// trans hops) serialized within each wave (compiler kept VGPR=84 -> no
// cross-element interleave), and 3-6 same-code waves/SIMD can't fill the
// holes. Here each cell runs: [all 24 MFMAs] -> [all 64 exp2] -> [all
// products] -> [all 16 rcp] -> [c-update + 16 exp2] -> [16 rcp + h] --
// every instruction has >=8 independent adjacent instances, so in-order
// issue never waits on trans latency. Registers: acc 64 + E 64 transient
// (~150 VGPR), launch_bounds(256,3) budget 170 -- above need, no r7 cliff.
// Recurrence stays register-resident (r10): packed bf16 h IS the next
// B-fragment under shared k-slot bijection phi(g,e)=e<4?g*4+e:16+g*4+e-4.
// Bias via h feature 31 == 1.0. C/D layout (verified r4-r11):
// col=lane&15, row=(lane>>4)*4+q.

#define HH 25
#define NSTEP 10
#define AOUT 18
#define WPB 4
#define BLK (WPB * 64)
#define NG 2      // independent batch groups per wave
#define NFRG 26   // 0..7 enc(Wih+Whh) | 8..15 decX | 16..23 decH | 24..25 actor
#define LOG2E 1.44269504088896340736f

typedef __attribute__((ext_vector_type(8))) short short8;
typedef __attribute__((ext_vector_type(4))) float f32x4;
typedef __attribute__((ext_vector_type(4))) unsigned u32x4;
typedef float f32x4u __attribute__((ext_vector_type(4), aligned(4)));

__device__ __forceinline__ short f2bf(float x) {   // f32 -> bf16 (RNE)
    unsigned u = __float_as_uint(x);
    u += 0x7fffu + ((u >> 16) & 1u);
    return (short)(u >> 16);
}
__device__ __forceinline__ unsigned cvtpk(float lo, float hi) {  // 2xf32 -> packed bf16
    unsigned rr;
    asm("v_cvt_pk_bf16_f32 %0, %1, %2" : "=v"(rr) : "v"(lo), "v"(hi));
    return rr;
}
#if __has_builtin(__builtin_amdgcn_exp2f)
#define EXP2(x) __builtin_amdgcn_exp2f(x)
#else
#define EXP2(x) exp2f(x)
#endif
#define RCP(x) __builtin_amdgcn_rcpf(x)
#define MFMA16(a, b, c) __builtin_amdgcn_mfma_f32_16x16x32_bf16((a), (b), (c), 0, 0, 0)

__global__ __launch_bounds__(BLK, 3)
void langnn_pm(const float* __restrict__ state,
               const float* __restrict__ Wih_e, const float* __restrict__ Whh_e,
               const float* __restrict__ bih_e, const float* __restrict__ bhh_e,
               const float* __restrict__ Wih_d, const float* __restrict__ Whh_d,
               const float* __restrict__ bih_d, const float* __restrict__ bhh_d,
               const float* __restrict__ Wact, const float* __restrict__ bact,
               float* __restrict__ out, int B)
{
    __shared__ __align__(16) short sFrag[NFRG][64][8];   // 26 KB, read-only after init

    const int tid  = threadIdx.x;
    const int lane = tid & 63;
    const int w    = tid >> 6;
    const int r    = lane & 15;    // B col (batch) / A row-within-tile
    const int g    = lane >> 4;    // k-chunk / C row-group

    // ---- build A-fragment (weight) table; bias in k-slot feature 31 ----
    for (int i = tid; i < NFRG * 64; i += BLK) {
        const int idx = i >> 6, l = i & 63;
        const int lj = l & 15, lg = l >> 4;
        const float *W1 = nullptr, *W2 = nullptr, *B1 = nullptr, *B2 = nullptr;
        int gt = 0, hf, rmax = HH;
        if (idx < 8)       { gt = idx >> 1;        hf = idx & 1; W1 = Wih_e; W2 = Whh_e; B1 = bih_e; B2 = bhh_e; }
        else if (idx < 16) { gt = (idx - 8) >> 1;  hf = idx & 1; W1 = Wih_d; B1 = bih_d; B2 = bhh_d; }
        else if (idx < 24) { gt = (idx - 16) >> 1; hf = idx & 1; W1 = Whh_d; }
        else               { hf = idx - 24;        W1 = Wact;    B1 = bact;  rmax = AOUT; }
        const bool actor = (idx >= 24);
        const float sc = actor ? 1.f : (gt == 2 ? 2.f * LOG2E : -LOG2E);
        const int row  = hf * 16 + lj;
        const int nrow = actor ? row : gt * HH + row;
        for (int e = 0; e < 8; ++e) {
            const int k = (e < 4) ? lg * 4 + e : 16 + lg * 4 + (e - 4);   // phi(lg,e)
            float v = 0.f;
            if (row < rmax) {
                if (k < HH) {
                    v = W1[nrow * HH + k];
                    if (W2) v += W2[nrow * HH + k];
                    v *= sc;
                } else if (k == 31 && B1) {
                    v = B1[nrow];
                    if (B2) v += B2[nrow];
                    v *= sc;
                }
            }
            sFrag[idx][l][e] = f2bf(v);
        }
    }
    __syncthreads();   // the only barrier

    const int b0 = (blockIdx.x * WPB + w) * (NG * 16);

    // cell states, element index el = hf*8 + u*4 + q
    float ce[16], cd[16];
    #pragma unroll
    for (int el = 0; el < 16; ++el) { ce[el] = 0.f; cd[el] = 0.f; }

    // initial B-fragments: hE = state (feature-31 slot = 1.0), hD = 0
    short8 hE[NG], hD[NG];
    #pragma unroll
    for (int u = 0; u < NG; ++u) {
        const float* sp = state + (size_t)(b0 + u * 16 + r) * HH;
        #pragma unroll
        for (int e = 0; e < 8; ++e) {
            const int k = (e < 4) ? g * 4 + e : 16 + g * 4 + (e - 4);
            hE[u][e] = (k < HH) ? f2bf(sp[k]) : (k == 31 ? (short)0x3F80 : (short)0);
            hD[u][e] = (k == 31) ? (short)0x3F80 : (short)0;
        }
    }

    auto packH8 = [&](float a0, float a1, float a2, float a3,
                      float b0_, float b1_, float b2_, float b3_) -> short8 {
        union { u32x4 d; short8 s; } un;
        un.d[0] = cvtpk(a0, a1);
        un.d[1] = cvtpk(a2, a3);
        un.d[2] = cvtpk(b0_, b1_);
        un.d[3] = cvtpk(b2_, (g == 3) ? 1.0f : b3_);   // feature 31 == 1.0
        return un.s;
    };
    auto storeEncU = [&](int t, int u, float h0, float h1, float h2, float h3,
                         float h4, float h5, float h6, float h7) {
        float* p = out + (size_t)B * AOUT + (size_t)t * B * HH + (size_t)(b0 + u * 16 + r) * HH;
        { f32x4u v; v[0] = h0; v[1] = h1; v[2] = h2; v[3] = h3; *(f32x4u*)(p + g * 4) = v; }
        if (g < 2) {
            f32x4u v; v[0] = h4; v[1] = h5; v[2] = h6; v[3] = h7;
            *(f32x4u*)(p + 16 + g * 4) = v;
        } else if (g == 2) {
            p[24] = h4;
        }
    };

    // phase-major activation over 16 elements; acc[hf][u][gt], cc = cell state
    // writes h into hv[16]
    #define ACT16(ACC, CC, HV)                                                  \
    {                                                                           \
        float Ei[16], Ef[16], Eg_[16], Eo[16];                                  \
        _Pragma("unroll") for (int hf = 0; hf < 2; ++hf)                        \
        _Pragma("unroll") for (int u = 0; u < NG; ++u)                          \
        _Pragma("unroll") for (int q = 0; q < 4; ++q) {                         \
            const int el = hf * 8 + u * 4 + q;                                  \
            Ei[el]  = EXP2(ACC[hf][u][0][q]);                                   \
            Ef[el]  = EXP2(ACC[hf][u][1][q]);                                   \
            Eg_[el] = EXP2(ACC[hf][u][2][q]);                                   \
            Eo[el]  = EXP2(ACC[hf][u][3][q]);                                   \
        }                                                                       \
        float R1[16], Cn[16], Pig[16];                                          \
        _Pragma("unroll") for (int el = 0; el < 16; ++el) {                     \
            float Pf = 1.f + Ef[el];                                            \
            Pig[el] = (1.f + Ei[el]) * (1.f + Eg_[el]);                         \
            R1[el] = RCP(Pf * Pig[el]);                                         \
            Cn[el] = fmaf(CC[el], Pig[el], (Eg_[el] - 1.f) * Pf);               \
        }                                                                       \
        float Ec[16];                                                           \
        _Pragma("unroll") for (int el = 0; el < 16; ++el) {                     \
            float c = Cn[el] * R1[el];                                          \
            CC[el] = c;                                                         \
            Ec[el] = EXP2(2.f * LOG2E * c);                                     \
        }                                                                       \
        _Pragma("unroll") for (int el = 0; el < 16; ++el) {                     \
            float R2 = RCP((1.f + Ec[el]) * (1.f + Eo[el]));                    \
            HV[el] = (Ec[el] - 1.f) * R2;                                       \
        }                                                                       \
    }

    // ---- enc step 0: W_ih-only frags built on the fly from global ----
    {
        f32x4 acc[2][NG][4];
        #pragma unroll
        for (int hf = 0; hf < 2; ++hf)
            #pragma unroll
            for (int gt = 0; gt < 4; ++gt) {
                const float sc = (gt == 2) ? 2.f * LOG2E : -LOG2E;
                const int row = hf * 16 + r;
                short8 Wf;
                #pragma unroll
                for (int e = 0; e < 8; ++e) {
                    const int k = (e < 4) ? g * 4 + e : 16 + g * 4 + (e - 4);
                    float v = 0.f;
                    if (row < HH) {
                        if (k < HH)       v = Wih_e[(gt * HH + row) * HH + k] * sc;
                        else if (k == 31) v = (bih_e[gt * HH + row] + bhh_e[gt * HH + row]) * sc;
                    }
                    Wf[e] = f2bf(v);
                }
                f32x4 z; z[0] = z[1] = z[2] = z[3] = 0.f;
                #pragma unroll
                for (int u = 0; u < NG; ++u) acc[hf][u][gt] = MFMA16(Wf, hE[u], z);
            }
        float hv[16];
        ACT16(acc, ce, hv);
        #pragma unroll
        for (int u = 0; u < NG; ++u) {
            storeEncU(0, u, hv[u * 4 + 0], hv[u * 4 + 1], hv[u * 4 + 2], hv[u * 4 + 3],
                      hv[8 + u * 4 + 0], hv[8 + u * 4 + 1], hv[8 + u * 4 + 2], hv[8 + u * 4 + 3]);
            hE[u] = packH8(hv[u * 4 + 0], hv[u * 4 + 1], hv[u * 4 + 2], hv[u * 4 + 3],
                           hv[8 + u * 4 + 0], hv[8 + u * 4 + 1], hv[8 + u * 4 + 2], hv[8 + u * 4 + 3]);
        }
    }

    #pragma unroll 1
    for (int t = 0; t < NSTEP - 1; ++t) {
        // ---- dec(t): 16 MFMAs clustered, then phase-major ACT ----
        {
            f32x4 acc[2][NG][4];
            #pragma unroll
            for (int hf = 0; hf < 2; ++hf)
                #pragma unroll
                for (int gt = 0; gt < 4; ++gt) {
                    short8 Wx = *(const short8*)&sFrag[8 + gt * 2 + hf][lane][0];
                    short8 Wh = *(const short8*)&sFrag[16 + gt * 2 + hf][lane][0];
                    f32x4 z; z[0] = z[1] = z[2] = z[3] = 0.f;
                    #pragma unroll
                    for (int u = 0; u < NG; ++u)
                        acc[hf][u][gt] = MFMA16(Wh, hD[u], MFMA16(Wx, hE[u], z));
                }
            float hv[16];
            ACT16(acc, cd, hv);
            #pragma unroll
            for (int u = 0; u < NG; ++u)
                hD[u] = packH8(hv[u * 4 + 0], hv[u * 4 + 1], hv[u * 4 + 2], hv[u * 4 + 3],
                               hv[8 + u * 4 + 0], hv[8 + u * 4 + 1], hv[8 + u * 4 + 2], hv[8 + u * 4 + 3]);
        }
        // ---- enc(t+1): 8 MFMAs clustered, then phase-major ACT ----
        {
            f32x4 acc[2][NG][4];
            #pragma unroll
            for (int hf = 0; hf < 2; ++hf)
                #pragma unroll
                for (int gt = 0; gt < 4; ++gt) {
                    short8 Wf = *(const short8*)&sFrag[gt * 2 + hf][lane][0];
                    f32x4 z; z[0] = z[1] = z[2] = z[3] = 0.f;
                    #pragma unroll
                    for (int u = 0; u < NG; ++u) acc[hf][u][gt] = MFMA16(Wf, hE[u], z);
                }
            float hv[16];
            ACT16(acc, ce, hv);
            #pragma unroll
            for (int u = 0; u < NG; ++u) {
                storeEncU(t + 1, u, hv[u * 4 + 0], hv[u * 4 + 1], hv[u * 4 + 2], hv[u * 4 + 3],
                          hv[8 + u * 4 + 0], hv[8 + u * 4 + 1], hv[8 + u * 4 + 2], hv[8 + u * 4 + 3]);
                hE[u] = packH8(hv[u * 4 + 0], hv[u * 4 + 1], hv[u * 4 + 2], hv[u * 4 + 3],
                               hv[8 + u * 4 + 0], hv[8 + u * 4 + 1], hv[8 + u * 4 + 2], hv[8 + u * 4 + 3]);
            }
        }
    }
    // ---- dec step 9 ----
    {
        f32x4 acc[2][NG][4];
        #pragma unroll
        for (int hf = 0; hf < 2; ++hf)
            #pragma unroll
            for (int gt = 0; gt < 4; ++gt) {
                short8 Wx = *(const short8*)&sFrag[8 + gt * 2 + hf][lane][0];
                short8 Wh = *(const short8*)&sFrag[16 + gt * 2 + hf][lane][0];
                f32x4 z; z[0] = z[1] = z[2] = z[3] = 0.f;
                #pragma unroll
                for (int u = 0; u < NG; ++u)
                    acc[hf][u][gt] = MFMA16(Wh, hD[u], MFMA16(Wx, hE[u], z));
            }
        float hv[16];
        ACT16(acc, cd, hv);
        #pragma unroll
        for (int u = 0; u < NG; ++u)
            hD[u] = packH8(hv[u * 4 + 0], hv[u * 4 + 1], hv[u * 4 + 2], hv[u * 4 + 3],
                           hv[8 + u * 4 + 0], hv[8 + u * 4 + 1], hv[8 + u * 4 + 2], hv[8 + u * 4 + 3]);
    }

    // ---- actor head (hD = hd(9); bias via feature-31 slot) ----
    {
        short8 W0 = *(const short8*)&sFrag[24][lane][0];
        short8 W1 = *(const short8*)&sFrag[25][lane][0];
        #pragma unroll
        for (int u = 0; u < NG; ++u) {
            f32x4 z; z[0] = z[1] = z[2] = z[3] = 0.f;
            f32x4 a0 = MFMA16(W0, hD[u], z);
            f32x4 a1 = MFMA16(W1, hD[u], z);
            float* p = out + (size_t)(b0 + u * 16 + r) * AOUT;
            f32x4u v; v[0] = a0[0]; v[1] = a0[1]; v[2] = a0[2]; v[3] = a0[3];
            *(f32x4u*)(p + g * 4) = v;                       // rows 0..15
            if (g == 0) { p[16] = a1[0]; p[17] = a1[1]; }    // rows 16..17
        }
    }
}

extern "C" void kernel_launch(void* const* d_in, const int* in_sizes, int n_in,
                              void* d_out, int out_size, void* d_ws, size_t ws_size,
                              hipStream_t stream) {
    const float* state = (const float*)d_in[0];
    const float* Wih_e = (const float*)d_in[1];
    const float* Whh_e = (const float*)d_in[2];
    const float* bih_e = (const float*)d_in[3];
    const float* bhh_e = (const float*)d_in[4];
    const float* Wih_d = (const float*)d_in[5];
    const float* Whh_d = (const float*)d_in[6];
    const float* bih_d = (const float*)d_in[7];
    const float* bhh_d = (const float*)d_in[8];
    const float* Wact  = (const float*)d_in[9];
    const float* bact  = (const float*)d_in[10];

    int B = in_sizes[0] / HH;
    int grid = B / (WPB * NG * 16);   // 131072/128 = 1024 blocks

    hipLaunchKernelGGL(langnn_pm, dim3(grid), dim3(BLK), 0, stream,
                       state, Wih_e, Whh_e, bih_e, bhh_e,
                       Wih_d, Whh_d, bih_d, bhh_d, Wact, bact,
                       (float*)d_out, B);
}

// Round 13
// 130.155 us; speedup vs baseline: 1.0082x; 1.0082x over previous
//
#include <hip/hip_runtime.h>

// LangNN via SWAPPED-operand 16x16x32 bf16 MFMA. B=131072, H=25, A=18.
// Round-13: r10 structure (NG=1, register-resident h recurrence) + ALL 24
// loop-invariant weight fragments HOISTED INTO REGISTERS (We/Wx/Wh, 96 VGPR).
// r6-r11 plateaued at ~60% VALUBusy: every loop iteration re-read 24 frags
// from LDS (compiler wouldn't hoist at its self-chosen 64-84 VGPR), exposing
// ~120-cyc lgkmcnt waits before each MFMA batch. Loop body is now pure
// register MFMA + VALU/trans + enc stores: no LDS, no lgkmcnt.
// Single-arg __launch_bounds__(256): the only config this allocator goes
// >128 VGPR without spilling (r3: 216 VGPR clean; r7/r12 min-waves arg
// collapsed to 40/84 + spill). Expect ~150-190 VGPR, 2-3 waves/SIMD --
// enough, since there's no latency left to hide except stores.
// Recurrence: packed bf16 h IS the next B-fragment under shared k-slot
// bijection phi(g,e)=e<4?g*4+e:16+g*4+e-4. Bias via h feature 31 == 1.0.
// C/D layout (verified r4-r12): col=lane&15, row=(lane>>4)*4+q.

#define HH 25
#define NSTEP 10
#define AOUT 18
#define WPB 4
#define BLK (WPB * 64)
#define NFRG 26   // 0..7 enc(Wih+Whh) | 8..15 decX | 16..23 decH | 24..25 actor
#define LOG2E 1.44269504088896340736f

typedef __attribute__((ext_vector_type(8))) short short8;
typedef __attribute__((ext_vector_type(4))) float f32x4;
typedef __attribute__((ext_vector_type(4))) unsigned u32x4;
typedef float f32x4u __attribute__((ext_vector_type(4), aligned(4)));

__device__ __forceinline__ short f2bf(float x) {   // f32 -> bf16 (RNE)
    unsigned u = __float_as_uint(x);
    u += 0x7fffu + ((u >> 16) & 1u);
    return (short)(u >> 16);
}
__device__ __forceinline__ unsigned cvtpk(float lo, float hi) {  // 2xf32 -> packed bf16
    unsigned rr;
    asm("v_cvt_pk_bf16_f32 %0, %1, %2" : "=v"(rr) : "v"(lo), "v"(hi));
    return rr;
}
#if __has_builtin(__builtin_amdgcn_exp2f)
#define EXP2(x) __builtin_amdgcn_exp2f(x)
#else
#define EXP2(x) exp2f(x)
#endif
#define RCP(x) __builtin_amdgcn_rcpf(x)
#define MFMA16(a, b, c) __builtin_amdgcn_mfma_f32_16x16x32_bf16((a), (b), (c), 0, 0, 0)

// one LSTM activation element: gates i,f,g,o pre-scaled by -log2e/+2log2e
#define ACT_ELEM(A0, A1, A2, A3, CREF, HOUT)                                   \
    {                                                                          \
        float Ei = EXP2(A0);                                                   \
        float Ef = EXP2(A1);                                                   \
        float Eg = EXP2(A2);                                                   \
        float Eo = EXP2(A3);                                                   \
        float Pf = 1.f + Ef;                                                   \
        float Pig = (1.f + Ei) * (1.f + Eg);                                   \
        float c = fmaf(CREF, Pig, (Eg - 1.f) * Pf) * RCP(Pf * Pig);            \
        CREF = c;                                                              \
        float Ec = EXP2(2.f * LOG2E * c);                                      \
        float Pc = 1.f + Ec;                                                   \
        HOUT = (Pc - 2.f) * RCP(Pc * (1.f + Eo));                              \
    }

__global__ __launch_bounds__(BLK)
void langnn_reg(const float* __restrict__ state,
                const float* __restrict__ Wih_e, const float* __restrict__ Whh_e,
                const float* __restrict__ bih_e, const float* __restrict__ bhh_e,
                const float* __restrict__ Wih_d, const float* __restrict__ Whh_d,
                const float* __restrict__ bih_d, const float* __restrict__ bhh_d,
                const float* __restrict__ Wact, const float* __restrict__ bact,
                float* __restrict__ out, int B)
{
    __shared__ __align__(16) short sFrag[NFRG][64][8];   // 26 KB; loop reads none of it

    const int tid  = threadIdx.x;
    const int lane = tid & 63;
    const int w    = tid >> 6;
    const int r    = lane & 15;    // B col (batch) / A row-within-tile
    const int g    = lane >> 4;    // k-chunk / C row-group

    // ---- build A-fragment (weight) table; bias in k-slot feature 31 ----
    for (int i = tid; i < NFRG * 64; i += BLK) {
        const int idx = i >> 6, l = i & 63;
        const int lj = l & 15, lg = l >> 4;
        const float *W1 = nullptr, *W2 = nullptr, *B1 = nullptr, *B2 = nullptr;
        int gt = 0, hf, rmax = HH;
        if (idx < 8)       { gt = idx >> 1;        hf = idx & 1; W1 = Wih_e; W2 = Whh_e; B1 = bih_e; B2 = bhh_e; }
        else if (idx < 16) { gt = (idx - 8) >> 1;  hf = idx & 1; W1 = Wih_d; B1 = bih_d; B2 = bhh_d; }
        else if (idx < 24) { gt = (idx - 16) >> 1; hf = idx & 1; W1 = Whh_d; }
        else               { hf = idx - 24;        W1 = Wact;    B1 = bact;  rmax = AOUT; }
        const bool actor = (idx >= 24);
        const float sc = actor ? 1.f : (gt == 2 ? 2.f * LOG2E : -LOG2E);
        const int row  = hf * 16 + lj;
        const int nrow = actor ? row : gt * HH + row;
        for (int e = 0; e < 8; ++e) {
            const int k = (e < 4) ? lg * 4 + e : 16 + lg * 4 + (e - 4);   // phi(lg,e)
            float v = 0.f;
            if (row < rmax) {
                if (k < HH) {
                    v = W1[nrow * HH + k];
                    if (W2) v += W2[nrow * HH + k];
                    v *= sc;
                } else if (k == 31 && B1) {
                    v = B1[nrow];
                    if (B2) v += B2[nrow];
                    v *= sc;
                }
            }
            sFrag[idx][l][e] = f2bf(v);
        }
    }
    __syncthreads();   // the only barrier

    // ---- hoist all loop-invariant frags into registers (96 VGPR) ----
    short8 We[8], Wx[8], Wh[8];
    #pragma unroll
    for (int i = 0; i < 8; ++i) {
        We[i] = *(const short8*)&sFrag[i][lane][0];
        Wx[i] = *(const short8*)&sFrag[8 + i][lane][0];
        Wh[i] = *(const short8*)&sFrag[16 + i][lane][0];
    }

    const int b0 = (blockIdx.x * WPB + w) * 16;

    float ce[2][4], cd[2][4];
    #pragma unroll
    for (int hf = 0; hf < 2; ++hf)
        #pragma unroll
        for (int q = 0; q < 4; ++q) { ce[hf][q] = 0.f; cd[hf][q] = 0.f; }

    // initial B-fragments: hE = state (feature-31 slot = 1.0), hD = 0
    short8 hE, hD;
    {
        const float* sp = state + (size_t)(b0 + r) * HH;
        #pragma unroll
        for (int e = 0; e < 8; ++e) {
            const int k = (e < 4) ? g * 4 + e : 16 + g * 4 + (e - 4);
            hE[e] = (k < HH) ? f2bf(sp[k]) : (k == 31 ? (short)0x3F80 : (short)0);
            hD[e] = (k == 31) ? (short)0x3F80 : (short)0;
        }
    }

    auto packH = [&](float (&hv)[2][4]) -> short8 {
        union { u32x4 d; short8 s; } un;
        un.d[0] = cvtpk(hv[0][0], hv[0][1]);
        un.d[1] = cvtpk(hv[0][2], hv[0][3]);
        un.d[2] = cvtpk(hv[1][0], hv[1][1]);
        un.d[3] = cvtpk(hv[1][2], (g == 3) ? 1.0f : hv[1][3]);   // feature 31 == 1.0
        return un.s;
    };
    auto storeEnc = [&](int t, float (&hv)[2][4]) {
        float* p = out + (size_t)B * AOUT + (size_t)t * B * HH + (size_t)(b0 + r) * HH;
        { f32x4u v; v[0] = hv[0][0]; v[1] = hv[0][1]; v[2] = hv[0][2]; v[3] = hv[0][3];
          *(f32x4u*)(p + g * 4) = v; }                            // features 0..15
        if (g < 2) {
            f32x4u v; v[0] = hv[1][0]; v[1] = hv[1][1]; v[2] = hv[1][2]; v[3] = hv[1][3];
            *(f32x4u*)(p + 16 + g * 4) = v;                       // features 16..23
        } else if (g == 2) {
            p[24] = hv[1][0];                                     // feature 24
        }
    };

    // ---- enc step 0: W_ih-only frags built on the fly from global ----
    {
        f32x4 acc[2][4];
        #pragma unroll
        for (int hf = 0; hf < 2; ++hf)
            #pragma unroll
            for (int gt = 0; gt < 4; ++gt) {
                const float sc = (gt == 2) ? 2.f * LOG2E : -LOG2E;
                const int row = hf * 16 + r;
                short8 Wf;
                #pragma unroll
                for (int e = 0; e < 8; ++e) {
                    const int k = (e < 4) ? g * 4 + e : 16 + g * 4 + (e - 4);
                    float v = 0.f;
                    if (row < HH) {
                        if (k < HH)       v = Wih_e[(gt * HH + row) * HH + k] * sc;
                        else if (k == 31) v = (bih_e[gt * HH + row] + bhh_e[gt * HH + row]) * sc;
                    }
                    Wf[e] = f2bf(v);
                }
                f32x4 z; z[0] = z[1] = z[2] = z[3] = 0.f;
                acc[hf][gt] = MFMA16(Wf, hE, z);
            }
        float hv[2][4];
        #pragma unroll
        for (int hf = 0; hf < 2; ++hf)
            #pragma unroll
            for (int q = 0; q < 4; ++q)
                ACT_ELEM(acc[hf][0][q], acc[hf][1][q], acc[hf][2][q], acc[hf][3][q],
                         ce[hf][q], hv[hf][q]);
        storeEnc(0, hv);
        hE = packH(hv);
    }

    // ---- fused loop: dec(t) + enc(t+1), both read hE(t); pure-register body ----
    #pragma unroll 1
    for (int t = 0; t < NSTEP - 1; ++t) {
        f32x4 accD[2][4], accE[2][4];
        #pragma unroll
        for (int hf = 0; hf < 2; ++hf)
            #pragma unroll
            for (int gt = 0; gt < 4; ++gt) {
                f32x4 z; z[0] = z[1] = z[2] = z[3] = 0.f;
                accD[hf][gt] = MFMA16(Wh[gt * 2 + hf], hD, MFMA16(Wx[gt * 2 + hf], hE, z));
                accE[hf][gt] = MFMA16(We[gt * 2 + hf], hE, z);
            }
        float hvD[2][4], hvE[2][4];
        #pragma unroll
        for (int hf = 0; hf < 2; ++hf)
            #pragma unroll
            for (int q = 0; q < 4; ++q) {
                ACT_ELEM(accD[hf][0][q], accD[hf][1][q], accD[hf][2][q], accD[hf][3][q],
                         cd[hf][q], hvD[hf][q]);
                ACT_ELEM(accE[hf][0][q], accE[hf][1][q], accE[hf][2][q], accE[hf][3][q],
                         ce[hf][q], hvE[hf][q]);
            }
        storeEnc(t + 1, hvE);
        hD = packH(hvD);
        hE = packH(hvE);
    }

    // ---- dec step 9 ----
    {
        f32x4 acc[2][4];
        #pragma unroll
        for (int hf = 0; hf < 2; ++hf)
            #pragma unroll
            for (int gt = 0; gt < 4; ++gt) {
                f32x4 z; z[0] = z[1] = z[2] = z[3] = 0.f;
                acc[hf][gt] = MFMA16(Wh[gt * 2 + hf], hD, MFMA16(Wx[gt * 2 + hf], hE, z));
            }
        float hv[2][4];
        #pragma unroll
        for (int hf = 0; hf < 2; ++hf)
            #pragma unroll
            for (int q = 0; q < 4; ++q)
                ACT_ELEM(acc[hf][0][q], acc[hf][1][q], acc[hf][2][q], acc[hf][3][q],
                         cd[hf][q], hv[hf][q]);
        hD = packH(hv);
    }

    // ---- actor head (hD = hd(9); bias via feature-31 slot; frags from LDS) ----
    {
        short8 W0 = *(const short8*)&sFrag[24][lane][0];
        short8 W1 = *(const short8*)&sFrag[25][lane][0];
        f32x4 z; z[0] = z[1] = z[2] = z[3] = 0.f;
        f32x4 a0 = MFMA16(W0, hD, z);
        f32x4 a1 = MFMA16(W1, hD, z);
        float* p = out + (size_t)(b0 + r) * AOUT;
        f32x4u v; v[0] = a0[0]; v[1] = a0[1]; v[2] = a0[2]; v[3] = a0[3];
        *(f32x4u*)(p + g * 4) = v;                       // rows 0..15
        if (g == 0) { p[16] = a1[0]; p[17] = a1[1]; }    // rows 16..17
    }
}

extern "C" void kernel_launch(void* const* d_in, const int* in_sizes, int n_in,
                              void* d_out, int out_size, void* d_ws, size_t ws_size,
                              hipStream_t stream) {
    const float* state = (const float*)d_in[0];
    const float* Wih_e = (const float*)d_in[1];
    const float* Whh_e = (const float*)d_in[2];
    const float* bih_e = (const float*)d_in[3];
    const float* bhh_e = (const float*)d_in[4];
    const float* Wih_d = (const float*)d_in[5];
    const float* Whh_d = (const float*)d_in[6];
    const float* bih_d = (const float*)d_in[7];
    const float* bhh_d = (const float*)d_in[8];
    const float* Wact  = (const float*)d_in[9];
    const float* bact  = (const float*)d_in[10];

    int B = in_sizes[0] / HH;
    int grid = B / (WPB * 16);   // 131072/64 = 2048 blocks

    hipLaunchKernelGGL(langnn_reg, dim3(grid), dim3(BLK), 0, stream,
                       state, Wih_e, Whh_e, bih_e, bhh_e,
                       Wih_d, Whh_d, bih_d, bhh_d, Wact, bact,
                       (float*)d_out, B);
}

// Round 14
// 96.276 us; speedup vs baseline: 1.3630x; 1.3519x over previous
//
#include <hip/hip_runtime.h>

// LangNN via 16x16x32 bf16 MFMA. B=131072, H=25, A=18.
// Round-14: r8 (best, 95.8us) with LDS cut 47104 -> 40960 B so the CU fits
// FOUR 512-thread blocks (32 waves/CU = 8/SIMD, VGPR 64 allows 8) instead of
// three; grid 1024 = 4 blocks/CU -> whole grid co-resident, no dispatch tail.
// Cuts: (1) actor frags out of LDS (built from global in epilogue), NFRG 26->24;
// (2) FPAD 40->32 (sH b128 reloads go 2->8-way bank conflict: ~+25cyc x2/step,
// negligible). Everything else byte-identical to r8.
// Evidence: busy = VALUBusy*dur ~= 57-61us in r6-r13 = computed VALU/trans
// issue floor; the 35us wall gap is latency exposure -> resident-wave count
// is the only untried lever (r13 killed the loop-LDS-latency theory).

#define HH 25
#define NSTEP 10
#define AOUT 18
#define WPB 8
#define BLK (WPB * 64)
#define NFRG 24   // 0..7 enc(Wih+Whh) | 8..15 decX | 16..23 decH
#define FPAD 32   // 64B row stride (16B-aligned b128; 8-way conflict, accepted)
#define LOG2E 1.44269504088896340736f

typedef __attribute__((ext_vector_type(8))) short short8;
typedef __attribute__((ext_vector_type(4))) float f32x4;

__device__ __forceinline__ short f2bf(float x) {   // f32 -> bf16 (RNE), init only
    unsigned u = __float_as_uint(x);
    u += 0x7fffu + ((u >> 16) & 1u);
    return (short)(u >> 16);
}
__device__ __forceinline__ unsigned cvtpk(float lo, float hi) {  // 2xf32 -> packed bf16
    unsigned r;
    asm("v_cvt_pk_bf16_f32 %0, %1, %2" : "=v"(r) : "v"(lo), "v"(hi));
    return r;
}
#if __has_builtin(__builtin_amdgcn_exp2f)
#define EXP2(x) __builtin_amdgcn_exp2f(x)
#else
#define EXP2(x) exp2f(x)
#endif
#define RCP(x) __builtin_amdgcn_rcpf(x)
#define MFMA16(a, b, c) __builtin_amdgcn_mfma_f32_16x16x32_bf16((a), (b), (c), 0, 0, 0)

__global__ __launch_bounds__(BLK, 4)
void langnn_mfma16(const float* __restrict__ state,
                   const float* __restrict__ Wih_e, const float* __restrict__ Whh_e,
                   const float* __restrict__ bih_e, const float* __restrict__ bhh_e,
                   const float* __restrict__ Wih_d, const float* __restrict__ Whh_d,
                   const float* __restrict__ bih_d, const float* __restrict__ bhh_d,
                   const float* __restrict__ Wact, const float* __restrict__ bact,
                   float* __restrict__ out, int B)
{
    __shared__ __align__(16) short sFrag[NFRG][64][8];      // 24 KB
    __shared__ __align__(16) short sH[2][WPB][16][FPAD];    // 16 KB ([0]=he, [1]=hd)

    const int tid  = threadIdx.x;
    const int lane = tid & 63;
    const int w    = tid >> 6;
    const int r    = lane & 15;    // A-row / C-col lane index
    const int g    = lane >> 4;    // k-group / C row-group

    // ---- build main B-fragment table (bias folded into k=25 row) ----
    for (int i = tid; i < NFRG * 64; i += BLK) {
        const int idx = i >> 6, l = i & 63;
        const int lj = l & 15, lg = l >> 4;
        const float *W1 = nullptr, *W2 = nullptr, *B1 = nullptr, *B2 = nullptr;
        int gt, jt;
        if (idx < 8)       { gt = idx >> 1;        jt = idx & 1; W1 = Wih_e; W2 = Whh_e; B1 = bih_e; B2 = bhh_e; }
        else if (idx < 16) { gt = (idx - 8) >> 1;  jt = idx & 1; W1 = Wih_d; B1 = bih_d; B2 = bhh_d; }
        else               { gt = (idx - 16) >> 1; jt = idx & 1; W1 = Whh_d; }
        const float sc = (gt == 2 ? 2.f * LOG2E : -LOG2E);
        const int col = jt * 16 + lj;
        const int nrow = gt * HH + col;
        for (int e = 0; e < 8; ++e) {
            const int k = lg * 8 + e;
            float v = 0.f;
            if (col < HH) {
                if (k < HH) {
                    v = W1[nrow * HH + k];
                    if (W2) v += W2[nrow * HH + k];
                    v *= sc;
                } else if (k == HH && B1) {
                    v = B1[nrow];
                    if (B2) v += B2[nrow];
                    v *= sc;
                }
            }
            sFrag[idx][l][e] = f2bf(v);
        }
    }
    // ---- build enc-step-0 W_ih frags ALIASED into sH[1] (hd region, 8 KB) ----
    {
        short* W0 = &sH[1][0][0][0];
        for (int i = tid; i < 8 * 64; i += BLK) {
            const int idx = i >> 6, l = i & 63;
            const int lj = l & 15, lg = l >> 4;
            const int gt = idx >> 1, jt = idx & 1;
            const float sc = (gt == 2 ? 2.f * LOG2E : -LOG2E);
            const int col = jt * 16 + lj;
            const int nrow = gt * HH + col;
            for (int e = 0; e < 8; ++e) {
                const int k = lg * 8 + e;
                float v = 0.f;
                if (col < HH) {
                    if (k < HH)       v = Wih_e[nrow * HH + k] * sc;
                    else if (k == HH) v = (bih_e[nrow] + bhh_e[nrow]) * sc;
                }
                W0[(size_t)idx * 512 + l * 8 + e] = f2bf(v);
            }
        }
    }
    // ---- init he region: zeros, col 25 = 1.0 (bias lane) ----
    {
        int* z = (int*)&sH[0][0][0][0];
        for (int i = tid; i < WPB * 16 * (FPAD / 2); i += BLK)
            z[i] = ((i % (FPAD / 2)) == 12) ? 0x3F800000 : 0;   // shorts 24|25 -> 0|1.0
    }
    __syncthreads();

    const int b0 = (blockIdx.x * WPB + w) * 16;
    float* pe = out + (size_t)B * AOUT + (size_t)(b0 + g * 4) * HH + r;

    float ce[2][4], cd[2][4];
    #pragma unroll
    for (int jt = 0; jt < 2; ++jt)
        #pragma unroll
        for (int q = 0; q < 4; ++q) { ce[jt][q] = 0.f; cd[jt][q] = 0.f; }

    // initial A-fragments: encoder x = state; decoder h = 0 (bias lane 1.0), in regs
    short8 aE, aD;
    {
        const float* sp0 = state + (size_t)(b0 + r) * HH;
        #pragma unroll
        for (int e = 0; e < 8; ++e) {
            const int k = g * 8 + e;
            aE[e] = (k < HH) ? f2bf(sp0[k]) : (k == HH ? (short)0x3F80 : (short)0);
            aD[e] = (k == HH) ? (short)0x3F80 : (short)0;
        }
    }

    auto encCell = [&](const short (*FB)[64][8]) {
        #pragma unroll
        for (int jt = 0; jt < 2; ++jt) {
            f32x4 acc[4];
            #pragma unroll
            for (int gt = 0; gt < 4; ++gt) {
                short8 Bf = *(const short8*)&FB[gt * 2 + jt][lane][0];
                f32x4 z; z[0] = z[1] = z[2] = z[3] = 0.f;
                acc[gt] = MFMA16(aE, Bf, z);
            }
            float hv[4];
            #pragma unroll
            for (int q = 0; q < 4; ++q) {
                float Ei = EXP2(acc[0][q]);
                float Ef = EXP2(acc[1][q]);
                float Eg = EXP2(acc[2][q]);
                float Eo = EXP2(acc[3][q]);
                float Pf = 1.f + Ef;
                float Pig = (1.f + Ei) * (1.f + Eg);
                float c = fmaf(ce[jt][q], Pig, (Eg - 1.f) * Pf) * RCP(Pf * Pig);
                ce[jt][q] = c;
                float Ec = EXP2(2.f * LOG2E * c);
                float Pc = 1.f + Ec;
                hv[q] = (Pc - 2.f) * RCP(Pc * (1.f + Eo));
            }
            if (jt == 0 || r < 9) {
                float* p = pe + jt * 16;
                p[0] = hv[0]; p[HH] = hv[1]; p[2 * HH] = hv[2]; p[3 * HH] = hv[3];
                unsigned p01 = cvtpk(hv[0], hv[1]), p23 = cvtpk(hv[2], hv[3]);
                short* sp = &sH[0][w][g * 4][jt * 16 + r];
                sp[0]        = (short)p01;
                sp[FPAD]     = (short)(p01 >> 16);
                sp[2 * FPAD] = (short)p23;
                sp[3 * FPAD] = (short)(p23 >> 16);
            }
        }
        aE = *(const short8*)&sH[0][w][r][g * 8];
        pe += (size_t)B * HH;
    };

    auto decCell = [&]() {
        #pragma unroll
        for (int jt = 0; jt < 2; ++jt) {
            f32x4 acc[4];
            #pragma unroll
            for (int gt = 0; gt < 4; ++gt) {
                short8 Bx = *(const short8*)&sFrag[8 + gt * 2 + jt][lane][0];
                short8 Bh = *(const short8*)&sFrag[16 + gt * 2 + jt][lane][0];
                f32x4 z; z[0] = z[1] = z[2] = z[3] = 0.f;
                acc[gt] = MFMA16(aD, Bh, MFMA16(aE, Bx, z));
            }
            float hv[4];
            #pragma unroll
            for (int q = 0; q < 4; ++q) {
                float Ei = EXP2(acc[0][q]);
                float Ef = EXP2(acc[1][q]);
                float Eg = EXP2(acc[2][q]);
                float Eo = EXP2(acc[3][q]);
                float Pf = 1.f + Ef;
                float Pig = (1.f + Ei) * (1.f + Eg);
                float c = fmaf(cd[jt][q], Pig, (Eg - 1.f) * Pf) * RCP(Pf * Pig);
                cd[jt][q] = c;
                float Ec = EXP2(2.f * LOG2E * c);
                float Pc = 1.f + Ec;
                hv[q] = (Pc - 2.f) * RCP(Pc * (1.f + Eo));
            }
            if (jt == 0 || r < 9) {
                unsigned p01 = cvtpk(hv[0], hv[1]), p23 = cvtpk(hv[2], hv[3]);
                short* sp = &sH[1][w][g * 4][jt * 16 + r];
                sp[0]        = (short)p01;
                sp[FPAD]     = (short)(p01 >> 16);
                sp[2 * FPAD] = (short)p23;
                sp[3 * FPAD] = (short)(p23 >> 16);
            }
        }
        aD = *(const short8*)&sH[1][w][r][g * 8];
    };

    // enc step 0 reads its frags from the sH[1] alias (all waves) ...
    encCell((const short (*)[64][8])&sH[1][0][0][0]);
    __syncthreads();   // ... so barrier before hd region is reclaimed
    {   // per-wave clear of own hd region: zeros, col 25 = 1.0
        int* z = (int*)&sH[1][w][0][0];
        for (int i = lane; i < 16 * (FPAD / 2); i += 64)
            z[i] = ((i % (FPAD / 2)) == 12) ? 0x3F800000 : 0;
    }
    decCell();                          // dec step 0
    #pragma unroll 1
    for (int t = 1; t < NSTEP; ++t) {
        encCell(sFrag);                 // enc step t (combined Wih+Whh frags)
        decCell();                      // dec step t
    }

    // ---- actor head: frags built from global (epilogue-only; L2-hit) ----
    #pragma unroll
    for (int jt = 0; jt < 2; ++jt) {
        const int col = jt * 16 + r;
        short8 Bf;
        #pragma unroll
        for (int e = 0; e < 8; ++e) {
            const int k = g * 8 + e;
            float v = 0.f;
            if (col < AOUT) {
                if (k < HH)       v = Wact[col * HH + k];
                else if (k == HH) v = bact[col];
            }
            Bf[e] = f2bf(v);
        }
        f32x4 z; z[0] = z[1] = z[2] = z[3] = 0.f;
        f32x4 o = MFMA16(aD, Bf, z);
        if (jt == 0 || r < 2) {
            float* p = out + (size_t)(b0 + g * 4) * AOUT + jt * 16 + r;
            p[0] = o[0]; p[AOUT] = o[1]; p[2 * AOUT] = o[2]; p[3 * AOUT] = o[3];
        }
    }
}

extern "C" void kernel_launch(void* const* d_in, const int* in_sizes, int n_in,
                              void* d_out, int out_size, void* d_ws, size_t ws_size,
                              hipStream_t stream) {
    const float* state = (const float*)d_in[0];
    const float* Wih_e = (const float*)d_in[1];
    const float* Whh_e = (const float*)d_in[2];
    const float* bih_e = (const float*)d_in[3];
    const float* bhh_e = (const float*)d_in[4];
    const float* Wih_d = (const float*)d_in[5];
    const float* Whh_d = (const float*)d_in[6];
    const float* bih_d = (const float*)d_in[7];
    const float* bhh_d = (const float*)d_in[8];
    const float* Wact  = (const float*)d_in[9];
    const float* bact  = (const float*)d_in[10];

    int B = in_sizes[0] / HH;
    int grid = B / (WPB * 16);   // 131072/128 = 1024 blocks = 4/CU, fully resident

    hipLaunchKernelGGL(langnn_mfma16, dim3(grid), dim3(BLK), 0, stream,
                       state, Wih_e, Whh_e, bih_e, bhh_e,
                       Wih_d, Whh_d, bih_d, bhh_d, Wact, bact,
                       (float*)d_out, B);
}